// Round 1
// baseline (947.749 us; speedup 1.0000x reference)
//
#include <hip/hip_runtime.h>
#include <hip/hip_fp16.h>
#include <math.h>

#define CCH 32  // channels per plane
#define CBITS 5
#define NCELLS (1 << (3 * CBITS))  // 32768 Morton cells

struct alignas(16) H8 { __half h[8]; };
typedef float vf4 __attribute__((ext_vector_type(4)));

// ---------------------------------------------------------------------------
// Transpose one plane: f32 [C=32, HW] -> f16 [HW, 32]
// ---------------------------------------------------------------------------
__global__ void __launch_bounds__(256) transpose_plane_kernel(
    const float* __restrict__ src, __half* __restrict__ dst, int HW) {
  __shared__ float tile[32][33];
  const int p0 = blockIdx.x * 32;
  const int tx = threadIdx.x & 31;
  const int ty = threadIdx.x >> 5;  // 0..7
#pragma unroll
  for (int ch = ty; ch < 32; ch += 8) {
    tile[ch][tx] = src[(size_t)ch * HW + p0 + tx];  // coalesced along pixels
  }
  __syncthreads();
#pragma unroll
  for (int py = ty; py < 32; py += 8) {
    dst[((size_t)(p0 + py)) * CCH + tx] = __float2half(tile[tx][py]);
  }
}

// ---------------------------------------------------------------------------
// Morton cell id: 5 bits/axis over [-1,1]^3 -> 15-bit interleaved code.
// ---------------------------------------------------------------------------
__device__ __forceinline__ int cell_of(float x, float y, float z) {
  int cx = (int)((x + 1.0f) * 16.0f);
  int cy = (int)((y + 1.0f) * 16.0f);
  int cz = (int)((z + 1.0f) * 16.0f);
  cx = min(max(cx, 0), 31);
  cy = min(max(cy, 0), 31);
  cz = min(max(cz, 0), 31);
  int m = 0;
#pragma unroll
  for (int b = 0; b < CBITS; b++) {
    m |= ((cx >> b) & 1) << (3 * b) | ((cy >> b) & 1) << (3 * b + 1) |
         ((cz >> b) & 1) << (3 * b + 2);
  }
  return m;
}

__global__ void __launch_bounds__(256) zero_hist_kernel(unsigned* hist) {
  hist[blockIdx.x * 256 + threadIdx.x] = 0u;
}

__global__ void __launch_bounds__(256) hist_kernel(
    const float* __restrict__ p_nor, unsigned* __restrict__ hist, int N) {
  const int i = blockIdx.x * blockDim.x + threadIdx.x;
  if (i >= N) return;
  const float x = p_nor[(size_t)i * 3 + 0];
  const float y = p_nor[(size_t)i * 3 + 1];
  const float z = p_nor[(size_t)i * 3 + 2];
  atomicAdd(&hist[cell_of(x, y, z)], 1u);
}

// Exclusive scan of NCELLS=32768 uints in place; single block of 1024 threads.
__global__ void __launch_bounds__(1024) scan_kernel(unsigned* __restrict__ hist) {
  __shared__ unsigned partial[1024];
  const int t = threadIdx.x;
  unsigned vals[32];
  unsigned sum = 0;
#pragma unroll
  for (int i = 0; i < 32; i++) {
    vals[i] = hist[t * 32 + i];
    sum += vals[i];
  }
  partial[t] = sum;
  __syncthreads();
  for (int off = 1; off < 1024; off <<= 1) {
    unsigned v = (t >= off) ? partial[t - off] : 0u;
    __syncthreads();
    partial[t] += v;
    __syncthreads();
  }
  unsigned base = (t == 0) ? 0u : partial[t - 1];
#pragma unroll
  for (int i = 0; i < 32; i++) {
    const unsigned v = vals[i];
    hist[t * 32 + i] = base;
    base += v;
  }
}

// Scatter points into Morton-sorted order: {x, y, z, bitcast(orig_idx)}.
__global__ void __launch_bounds__(256) scatter_kernel(
    const float* __restrict__ p_nor, unsigned* __restrict__ offs,
    float4* __restrict__ ps, int N) {
  const int i = blockIdx.x * blockDim.x + threadIdx.x;
  if (i >= N) return;
  const float x = p_nor[(size_t)i * 3 + 0];
  const float y = p_nor[(size_t)i * 3 + 1];
  const float z = p_nor[(size_t)i * 3 + 2];
  const unsigned pos = atomicAdd(&offs[cell_of(x, y, z)], 1u);
  float4 v;
  v.x = x; v.y = y; v.z = z; v.w = __int_as_float(i);
  ps[pos] = v;
}

// ---------------------------------------------------------------------------
// Gather over Morton-sorted points. thread = (sorted point, channel-octet).
// oct 0..3 -> level 0 (R0), oct 4..7 -> level 1 (R1); 8 channels each.
// Bijective XCD-chunk swizzle so each XCD's L2 sees one contiguous Morton
// range (T1 / m204 formula).
// ---------------------------------------------------------------------------
__global__ void __launch_bounds__(256) gather_sorted_kernel(
    const float4* __restrict__ ps, const __half* __restrict__ planes,
    float* __restrict__ out, int N, int R0, int R1, size_t lvl1_off) {
  const int nwg = gridDim.x;
  const int q = nwg >> 3, r = nwg & 7;
  const int xcd = blockIdx.x & 7;
  const int lin = blockIdx.x >> 3;
  const int wg = (xcd < r ? xcd * (q + 1) : r * (q + 1) + (xcd - r) * q) + lin;

  const int tid = wg * 256 + (int)threadIdx.x;
  const int idx = tid >> 3;
  if (idx >= N) return;
  const int oct = tid & 7;
  const int level = oct >> 2;
  const int chb = (oct & 3) << 3;

  const float4 p = ps[idx];
  const int pt = __float_as_int(p.w);

  const int R = level ? R1 : R0;
  const float Rm1 = (float)(R - 1);
  const __half* pb = planes + (level ? lvl1_off : 0) + chb;
  const size_t planeStride = (size_t)R * R * CCH;

  float acc[8];
#pragma unroll
  for (int j = 0; j < 8; j++) acc[j] = 0.0f;

  const float gx[3] = {p.x, p.x, p.y};
  const float gy[3] = {p.y, p.z, p.z};

#pragma unroll
  for (int k = 0; k < 3; k++) {
    float fx = (gx[k] + 1.0f) * 0.5f * Rm1;
    float fy = (gy[k] + 1.0f) * 0.5f * Rm1;
    fx = fminf(fmaxf(fx, 0.0f), Rm1);
    fy = fminf(fmaxf(fy, 0.0f), Rm1);
    const float x0f = floorf(fx);
    const float y0f = floorf(fy);
    const int x0 = (int)x0f;
    const int y0 = (int)y0f;
    const int x1 = min(x0 + 1, R - 1);
    const int y1 = min(y0 + 1, R - 1);
    const float wx = fx - x0f;
    const float wy = fy - y0f;
    const float w00 = (1.0f - wx) * (1.0f - wy);
    const float w10 = wx * (1.0f - wy);
    const float w01 = (1.0f - wx) * wy;
    const float w11 = wx * wy;

    const __half* pl = pb + (size_t)k * planeStride;
    const H8 a = *(const H8*)(pl + ((size_t)y0 * R + x0) * CCH);
    const H8 b = *(const H8*)(pl + ((size_t)y0 * R + x1) * CCH);
    const H8 c = *(const H8*)(pl + ((size_t)y1 * R + x0) * CCH);
    const H8 d = *(const H8*)(pl + ((size_t)y1 * R + x1) * CCH);
#pragma unroll
    for (int j = 0; j < 8; j++) {
      acc[j] += __half2float(a.h[j]) * w00 + __half2float(b.h[j]) * w10 +
                __half2float(c.h[j]) * w01 + __half2float(d.h[j]) * w11;
    }
  }

  vf4* o = (vf4*)(out + (size_t)pt * 64 + (size_t)oct * 8);
  vf4 v0 = {acc[0], acc[1], acc[2], acc[3]};
  vf4 v1 = {acc[4], acc[5], acc[6], acc[7]};
  __builtin_nontemporal_store(v0, o);
  __builtin_nontemporal_store(v1, o + 1);
}

// ---------------------------------------------------------------------------
// Fallback 1: unsorted f16 gather (previous best path).
// ---------------------------------------------------------------------------
__global__ void __launch_bounds__(256) gather_kernel(
    const float* __restrict__ p_nor, const __half* __restrict__ planes,
    float* __restrict__ out, int N, int R0, int R1, size_t lvl1_off) {
  const int tid = blockIdx.x * blockDim.x + threadIdx.x;
  const int pt = tid >> 3;
  if (pt >= N) return;
  const int oct = tid & 7;
  const int level = oct >> 2;
  const int chb = (oct & 3) << 3;

  const float q0 = p_nor[(size_t)pt * 3 + 0];
  const float q1 = p_nor[(size_t)pt * 3 + 1];
  const float q2 = p_nor[(size_t)pt * 3 + 2];

  const int R = level ? R1 : R0;
  const float Rm1 = (float)(R - 1);
  const __half* pb = planes + (level ? lvl1_off : 0) + chb;
  const size_t planeStride = (size_t)R * R * CCH;

  float acc[8];
#pragma unroll
  for (int j = 0; j < 8; j++) acc[j] = 0.0f;

  const float gx[3] = {q0, q0, q1};
  const float gy[3] = {q1, q2, q2};

#pragma unroll
  for (int k = 0; k < 3; k++) {
    float fx = (gx[k] + 1.0f) * 0.5f * Rm1;
    float fy = (gy[k] + 1.0f) * 0.5f * Rm1;
    fx = fminf(fmaxf(fx, 0.0f), Rm1);
    fy = fminf(fmaxf(fy, 0.0f), Rm1);
    const float x0f = floorf(fx);
    const float y0f = floorf(fy);
    const int x0 = (int)x0f;
    const int y0 = (int)y0f;
    const int x1 = min(x0 + 1, R - 1);
    const int y1 = min(y0 + 1, R - 1);
    const float wx = fx - x0f;
    const float wy = fy - y0f;
    const float w00 = (1.0f - wx) * (1.0f - wy);
    const float w10 = wx * (1.0f - wy);
    const float w01 = (1.0f - wx) * wy;
    const float w11 = wx * wy;

    const __half* pl = pb + (size_t)k * planeStride;
    const H8 a = *(const H8*)(pl + ((size_t)y0 * R + x0) * CCH);
    const H8 b = *(const H8*)(pl + ((size_t)y0 * R + x1) * CCH);
    const H8 c = *(const H8*)(pl + ((size_t)y1 * R + x0) * CCH);
    const H8 d = *(const H8*)(pl + ((size_t)y1 * R + x1) * CCH);
#pragma unroll
    for (int j = 0; j < 8; j++) {
      acc[j] += __half2float(a.h[j]) * w00 + __half2float(b.h[j]) * w10 +
                __half2float(c.h[j]) * w01 + __half2float(d.h[j]) * w11;
    }
  }

  vf4* o = (vf4*)(out + (size_t)pt * 64 + (size_t)oct * 8);
  vf4 v0 = {acc[0], acc[1], acc[2], acc[3]};
  vf4 v1 = {acc[4], acc[5], acc[6], acc[7]};
  __builtin_nontemporal_store(v0, o);
  __builtin_nontemporal_store(v1, o + 1);
}

// ---------------------------------------------------------------------------
// Fallback 2 (ws too small): direct gather from original f32 [C,H,W] planes.
// ---------------------------------------------------------------------------
__global__ void __launch_bounds__(256) gather_direct_kernel(
    const float* __restrict__ p_nor, const float* __restrict__ xy0,
    const float* __restrict__ xz0, const float* __restrict__ yz0,
    const float* __restrict__ xy1, const float* __restrict__ xz1,
    const float* __restrict__ yz1, float* __restrict__ out, int N, int R0,
    int R1) {
  const int tid = blockIdx.x * blockDim.x + threadIdx.x;
  const int pt = tid >> 6;
  if (pt >= N) return;
  const int c = tid & 63;
  const int level = c >> 5;
  const int ch = c & 31;

  const float q0 = p_nor[(size_t)pt * 3 + 0];
  const float q1 = p_nor[(size_t)pt * 3 + 1];
  const float q2 = p_nor[(size_t)pt * 3 + 2];

  const int R = level ? R1 : R0;
  const float Rm1 = (float)(R - 1);
  const size_t HW = (size_t)R * R;

  const float* pls[3];
  if (level) {
    pls[0] = xy1; pls[1] = xz1; pls[2] = yz1;
  } else {
    pls[0] = xy0; pls[1] = xz0; pls[2] = yz0;
  }
  const float gx[3] = {q0, q0, q1};
  const float gy[3] = {q1, q2, q2};

  float acc = 0.0f;
#pragma unroll
  for (int k = 0; k < 3; k++) {
    float fx = (gx[k] + 1.0f) * 0.5f * Rm1;
    float fy = (gy[k] + 1.0f) * 0.5f * Rm1;
    fx = fminf(fmaxf(fx, 0.0f), Rm1);
    fy = fminf(fmaxf(fy, 0.0f), Rm1);
    const float x0f = floorf(fx);
    const float y0f = floorf(fy);
    const int x0 = (int)x0f;
    const int y0 = (int)y0f;
    const int x1 = min(x0 + 1, R - 1);
    const int y1 = min(y0 + 1, R - 1);
    const float wx = fx - x0f;
    const float wy = fy - y0f;
    const float* p = pls[k] + (size_t)ch * HW;
    const float p00 = p[(size_t)y0 * R + x0];
    const float p10 = p[(size_t)y0 * R + x1];
    const float p01 = p[(size_t)y1 * R + x0];
    const float p11 = p[(size_t)y1 * R + x1];
    acc += (p00 * (1.0f - wx) + p10 * wx) * (1.0f - wy) +
           (p01 * (1.0f - wx) + p11 * wx) * wy;
  }
  out[(size_t)pt * 64 + c] = acc;
}

extern "C" void kernel_launch(void* const* d_in, const int* in_sizes, int n_in,
                              void* d_out, int out_size, void* d_ws,
                              size_t ws_size, hipStream_t stream) {
  const float* p_nor = (const float*)d_in[0];
  const float* xy0 = (const float*)d_in[1];
  const float* xz0 = (const float*)d_in[2];
  const float* yz0 = (const float*)d_in[3];
  const float* xy1 = (const float*)d_in[4];
  const float* xz1 = (const float*)d_in[5];
  const float* yz1 = (const float*)d_in[6];
  float* out = (float*)d_out;

  const int N = in_sizes[0] / 3;
  const int HW0 = in_sizes[1] / CCH;  // 16384 (128^2)
  const int HW1 = in_sizes[4] / CCH;  // 262144 (512^2)
  const int R0 = (int)(sqrtf((float)HW0) + 0.5f);
  const int R1 = (int)(sqrtf((float)HW1) + 0.5f);

  const size_t s0 = (size_t)HW0 * CCH;  // elems per level-0 plane
  const size_t s1 = (size_t)HW1 * CCH;  // elems per level-1 plane
  const size_t tpBytes = (3 * s0 + 3 * s1) * sizeof(__half);

  // Workspace layout for sorted path: [tp f16 planes][hist u32][ps float4]
  const size_t histOff = (tpBytes + 255) & ~(size_t)255;
  const size_t histBytes = (size_t)NCELLS * sizeof(unsigned);
  const size_t psOff = (histOff + histBytes + 255) & ~(size_t)255;
  const size_t psBytes = (size_t)N * sizeof(float4);
  const size_t needSort = psOff + psBytes;
  const size_t needF16 = tpBytes;

  const int ptBlocks = (N + 255) / 256;

  if (ws_size >= needSort) {
    __half* tp = (__half*)d_ws;
    unsigned* hist = (unsigned*)((char*)d_ws + histOff);
    float4* ps = (float4*)((char*)d_ws + psOff);

    // f16 [HW,32] transposes
    transpose_plane_kernel<<<HW0 / 32, 256, 0, stream>>>(xy0, tp + 0 * s0, HW0);
    transpose_plane_kernel<<<HW0 / 32, 256, 0, stream>>>(xz0, tp + 1 * s0, HW0);
    transpose_plane_kernel<<<HW0 / 32, 256, 0, stream>>>(yz0, tp + 2 * s0, HW0);
    transpose_plane_kernel<<<HW1 / 32, 256, 0, stream>>>(xy1, tp + 3 * s0 + 0 * s1, HW1);
    transpose_plane_kernel<<<HW1 / 32, 256, 0, stream>>>(xz1, tp + 3 * s0 + 1 * s1, HW1);
    transpose_plane_kernel<<<HW1 / 32, 256, 0, stream>>>(yz1, tp + 3 * s0 + 2 * s1, HW1);

    // Morton counting sort
    zero_hist_kernel<<<NCELLS / 256, 256, 0, stream>>>(hist);
    hist_kernel<<<ptBlocks, 256, 0, stream>>>(p_nor, hist, N);
    scan_kernel<<<1, 1024, 0, stream>>>(hist);
    scatter_kernel<<<ptBlocks, 256, 0, stream>>>(p_nor, hist, ps, N);

    // Gather in sorted order
    const long long threads = (long long)N * 8;
    const int blocks = (int)((threads + 255) / 256);
    gather_sorted_kernel<<<blocks, 256, 0, stream>>>(ps, tp, out, N, R0, R1,
                                                     3 * s0);
  } else if (ws_size >= needF16) {
    __half* tp = (__half*)d_ws;
    transpose_plane_kernel<<<HW0 / 32, 256, 0, stream>>>(xy0, tp + 0 * s0, HW0);
    transpose_plane_kernel<<<HW0 / 32, 256, 0, stream>>>(xz0, tp + 1 * s0, HW0);
    transpose_plane_kernel<<<HW0 / 32, 256, 0, stream>>>(yz0, tp + 2 * s0, HW0);
    transpose_plane_kernel<<<HW1 / 32, 256, 0, stream>>>(xy1, tp + 3 * s0 + 0 * s1, HW1);
    transpose_plane_kernel<<<HW1 / 32, 256, 0, stream>>>(xz1, tp + 3 * s0 + 1 * s1, HW1);
    transpose_plane_kernel<<<HW1 / 32, 256, 0, stream>>>(yz1, tp + 3 * s0 + 2 * s1, HW1);

    const long long threads = (long long)N * 8;
    const int blocks = (int)((threads + 255) / 256);
    gather_kernel<<<blocks, 256, 0, stream>>>(p_nor, tp, out, N, R0, R1,
                                              3 * s0);
  } else {
    const long long threads = (long long)N * 64;
    const int blocks = (int)((threads + 255) / 256);
    gather_direct_kernel<<<blocks, 256, 0, stream>>>(
        p_nor, xy0, xz0, yz0, xy1, xz1, yz1, out, N, R0, R1);
  }
}